// Round 12
// baseline (343.742 us; speedup 1.0000x reference)
//
#include <hip/hip_runtime.h>
#include <hip/hip_bf16.h>
#include <cstdint>
#include <cstddef>

#define NNODES 100000
#define NEDGES 3200000
#define NTOT   3300000   // edges + self loops
#define FIN    256
#define HH     64        // heads*hid (layer 1 out)
#define NH     8
#define C2     40
#define NEG    0.2f

// counting-sort params
#define CHUNK  8192
#define NBLK   403       // ceil(NTOT/CHUNK)
#define NBKT   391       // ceil(NNODES/256); bucket(d) = d>>8
#define GEMM1_BLKS 1563  // ceil(NNODES/64)

typedef __hip_bfloat16 bf16;
typedef __attribute__((ext_vector_type(8))) short short8;
typedef __attribute__((ext_vector_type(4))) float f32x4;

// ---------------- fused front-1: bucket histogram (blocks < NBLK) || W1 fragment convert ----------------

__global__ __launch_bounds__(256) void k_front1(const int* __restrict__ ei, int* __restrict__ bhist,
                                                const float* __restrict__ W, bf16* __restrict__ Wf) {
    int t = threadIdx.x;
    if (blockIdx.x < NBLK) {
        __shared__ int h[NBKT];
        for (int b = t; b < NBKT; b += 256) h[b] = 0;
        __syncthreads();
        int i0 = blockIdx.x * CHUNK;
        int i1 = i0 + CHUNK; if (i1 > NTOT) i1 = NTOT;
        for (int i = i0 + t; i < i1; i += 256) {
            int d = (i < NEDGES) ? ei[NEDGES + i] : (i - NEDGES);
            atomicAdd(&h[d >> 8], 1);      // LDS atomic
        }
        __syncthreads();
        for (int b = t; b < NBKT; b += 256) bhist[b * NBLK + blockIdx.x] = h[b];
    } else {
        // W1[256,64] f32 -> Wf bf16 fragment order: Wf[((s*4+f)*64+l)*8+j] = W1[s*32+(l>>4)*8+j][16f+(l&15)]
        int idx = (blockIdx.x - NBLK) * 256 + t;  // < 16384, exact (64 blocks)
        int j = idx & 7, slot = idx >> 3;
        int l = slot & 63, sf = slot >> 6;
        int s = sf >> 2, f = sf & 3;
        int k = s * 32 + (l >> 4) * 8 + j;
        int c = 16 * f + (l & 15);
        Wf[idx] = __float2bfloat16(W[k * HH + c]);
    }
}

// ---------------- CSR scans ----------------

__global__ __launch_bounds__(512) void k_bscan(int* __restrict__ bhist, int* __restrict__ bktTot) {
    __shared__ int sm[512];
    int t = threadIdx.x, b = blockIdx.x;
    int v = (t < NBLK) ? bhist[b * NBLK + t] : 0;
    sm[t] = v;
    __syncthreads();
    for (int off = 1; off < 512; off <<= 1) {
        int u = (t >= off) ? sm[t - off] : 0;
        __syncthreads();
        sm[t] += u;
        __syncthreads();
    }
    if (t < NBLK) bhist[b * NBLK + t] = sm[t] - v;   // exclusive prefix within bucket
    if (t == NBLK - 1) bktTot[b] = sm[t];
}

__global__ __launch_bounds__(512) void k_base(const int* __restrict__ bktTot, int* __restrict__ bktBase,
                                              int* __restrict__ rowptr) {
    __shared__ int sm[512];
    int t = threadIdx.x;
    int v = (t < NBKT) ? bktTot[t] : 0;
    sm[t] = v;
    __syncthreads();
    for (int off = 1; off < 512; off <<= 1) {
        int u = (t >= off) ? sm[t - off] : 0;
        __syncthreads();
        sm[t] += u;
        __syncthreads();
    }
    if (t < NBKT) bktBase[t] = sm[t] - v;
    if (t == NBKT - 1) bktBase[NBKT] = sm[t];
    if (t == 0) rowptr[NNODES] = NTOT;
}

// ---------------- fused front-2: edge scatter (blocks < NBLK) || MFMA gemm1 ----------------

__global__ __launch_bounds__(256) void k_front2(const int* __restrict__ ei, const int* __restrict__ bhist,
                                                const int* __restrict__ bktBase, unsigned int* __restrict__ pb,
                                                const float* __restrict__ x, const bf16* __restrict__ Wf,
                                                const float* __restrict__ asw, const float* __restrict__ adw,
                                                bf16* __restrict__ h1b, float* __restrict__ as,
                                                float* __restrict__ ad) {
    __shared__ int cur[NBKT];
    __shared__ short xs[64][256];   // bf16 bits, 8-elem blocks swizzled: kb' = kb ^ (row&7)
    int t = threadIdx.x;
    if (blockIdx.x < NBLK) {
        // ---- scat1: place packed (src<<8 | dst&255) into bucket-major order via LDS cursors ----
        int blk = blockIdx.x;
        for (int b = t; b < NBKT; b += 256) cur[b] = bktBase[b] + bhist[b * NBLK + blk];
        __syncthreads();
        int i0 = blk * CHUNK;
        int i1 = i0 + CHUNK; if (i1 > NTOT) i1 = NTOT;
        for (int i = i0 + t; i < i1; i += 256) {
            int s, d;
            if (i < NEDGES) { s = ei[i]; d = ei[NEDGES + i]; }
            else            { s = d = i - NEDGES; }
            int p = atomicAdd(&cur[d >> 8], 1);   // LDS atomic
            pb[p] = ((unsigned)s << 8) | (unsigned)(d & 255);
        }
        return;
    }
    // ---- gemm1: h1b[N,64](bf16) = x @ W1 via mfma_f32_16x16x32_bf16; fused att dots ----
    int n0 = (blockIdx.x - NBLK) * 64;
    {
        int r = t >> 2, cq = t & 3;
        int n = n0 + r; if (n >= NNODES) n = NNODES - 1;   // clamp loads; stores guarded
        const float4* xr = (const float4*)(x + (size_t)n * FIN + cq * 64);
        int sw = r & 7;
#pragma unroll
        for (int u = 0; u < 8; ++u) {
            float4 p0 = xr[2 * u], p1 = xr[2 * u + 1];
            float tmp[8] = {p0.x, p0.y, p0.z, p0.w, p1.x, p1.y, p1.z, p1.w};
            short8 v;
#pragma unroll
            for (int e = 0; e < 8; ++e) {
                bf16 b = __float2bfloat16(tmp[e]);
                v[e] = *reinterpret_cast<short*>(&b);
            }
            int kb = cq * 8 + u;
            *(short8*)&xs[r][(kb ^ sw) << 3] = v;
        }
    }
    __syncthreads();
    int l = t & 63, wv = t >> 6;
    int rbase = wv * 16;
    int lr = l & 15, g = l >> 4;
    f32x4 acc[4] = {{0.f,0.f,0.f,0.f},{0.f,0.f,0.f,0.f},{0.f,0.f,0.f,0.f},{0.f,0.f,0.f,0.f}};
    const short8* wfp = (const short8*)Wf;
#pragma unroll 2
    for (int s = 0; s < 8; ++s) {
        short8 a = *(const short8*)&xs[rbase + lr][((s * 4 + g) ^ (lr & 7)) << 3];
#pragma unroll
        for (int f = 0; f < 4; ++f) {
            short8 b = wfp[(s * 4 + f) * 64 + l];
            acc[f] = __builtin_amdgcn_mfma_f32_16x16x32_bf16(a, b, acc[f], 0, 0, 0);
        }
    }
    float awf[4], dwf[4];
#pragma unroll
    for (int f = 0; f < 4; ++f) { awf[f] = asw[16 * f + lr]; dwf[f] = adw[16 * f + lr]; }
    float svv[4][4], dvv[4][4];
#pragma unroll
    for (int f = 0; f < 4; ++f) {
#pragma unroll
        for (int j = 0; j < 4; ++j) {
            float val = acc[f][j];
            int n = n0 + rbase + g * 4 + j;
            if (n < NNODES) h1b[(size_t)n * HH + 16 * f + lr] = __float2bfloat16(val);
            float sv = val * awf[f], dv = val * dwf[f];
            sv += __shfl_xor(sv, 1); sv += __shfl_xor(sv, 2); sv += __shfl_xor(sv, 4);
            dv += __shfl_xor(dv, 1); dv += __shfl_xor(dv, 2); dv += __shfl_xor(dv, 4);
            svv[f][j] = sv; dvv[f][j] = dv;
        }
    }
    if ((l & 7) == 0) {
        int hb = (l >> 3) & 1;   // head = 2f + hb
#pragma unroll
        for (int f = 0; f < 4; ++f) {
            int h = 2 * f + hb;
#pragma unroll
            for (int j = 0; j < 4; ++j) {
                int n = n0 + rbase + g * 4 + j;
                if (n < NNODES) { as[n * NH + h] = svv[f][j]; ad[n * NH + h] = dvv[f][j]; }
            }
        }
    }
}

// ---------------- bucket pass: per-node x per-src-chunk deg + scan + cursors in LDS ----------------
// Orders each node's edge list by source chunk (src>>15, 4 chunks of <=32768 nodes) so that all
// waves in the aggregation kernels walk chunk-0 sources first, then chunk-1, ... -> the per-XCD L2
// only needs one chunk's rows (h1b: 4MB, h2b: 2MB, as1: 1MB) at a time. Pure reorder: acc/den are
// order-invariant sums, so results are identical up to fp reassociation.

__global__ __launch_bounds__(256) void k_bucket(const unsigned int* __restrict__ pb,
                                                const int* __restrict__ bktBase,
                                                int* __restrict__ rowptr, int* __restrict__ esrc) {
    __shared__ int dcnt[1024];   // [node_local][src_chunk]
    __shared__ int sm[256];
    __shared__ int cur[1024];
    int t = threadIdx.x, b = blockIdx.x;
    int base = bktBase[b], cnt = bktBase[b + 1] - base;
    dcnt[t] = 0; dcnt[t + 256] = 0; dcnt[t + 512] = 0; dcnt[t + 768] = 0;
    __syncthreads();
    for (int i = t; i < cnt; i += 256) {
        unsigned int e = pb[base + i];
        atomicAdd(&dcnt[(int)(e & 255u) * 4 + (int)(e >> 23)], 1);  // chunk = src>>15 = e>>23
    }
    __syncthreads();
    int c0 = dcnt[t * 4], c1 = dcnt[t * 4 + 1], c2 = dcnt[t * 4 + 2], c3 = dcnt[t * 4 + 3];
    int tot = ((c0 + c1) + (c2 + c3));
    sm[t] = tot;
    __syncthreads();
    for (int off = 1; off < 256; off <<= 1) {
        int u = (t >= off) ? sm[t - off] : 0;
        __syncthreads();
        sm[t] += u;
        __syncthreads();
    }
    int ex = sm[t] - tot;
    int n = (b << 8) + t;
    if (n < NNODES) rowptr[n] = base + ex;
    cur[t * 4]     = base + ex;
    cur[t * 4 + 1] = base + ex + c0;
    cur[t * 4 + 2] = base + ex + c0 + c1;
    cur[t * 4 + 3] = base + ex + c0 + c1 + c2;
    __syncthreads();
    for (int i = t; i < cnt; i += 256) {
        unsigned int e = pb[base + i];
        int p = atomicAdd(&cur[(int)(e & 255u) * 4 + (int)(e >> 23)], 1);  // LDS atomic
        esrc[p] = (int)(e >> 8);
    }
}

// ---------------- Layer 1 aggregation (r8 structure, unchanged) ----------------

// one wave per node; e-phase: 8 edges x 8 heads -> weights in per-wave LDS tile; den in e-phase.
// fma-phase: s via uniform s_load, SGPR row base, weight via LDS [k*8+h]; pipelined prefetch.
__global__ __launch_bounds__(256) void k_aggr1(const bf16* __restrict__ h1b, const float* __restrict__ as,
                                               const float* __restrict__ ad, const int* __restrict__ rowptr,
                                               const int* __restrict__ esrc, const float* __restrict__ b1,
                                               float* __restrict__ hmid) {
    __shared__ float wlds[4][64];
    int wv = threadIdx.x >> 6, t = threadIdx.x & 63;
    int n = blockIdx.x * 4 + wv;
    int ih = t & 7;   // e-phase head
    int ie = t >> 3;  // e-phase edge slot
    int h  = t >> 3;  // fma-phase: head of channel t
    float adh = ad[n * NH + ih];
    int beg = __builtin_amdgcn_readfirstlane(rowptr[n]);
    int end = __builtin_amdgcn_readfirstlane(rowptr[n + 1]);
    float acc = 0.f, den_e = 0.f;
    // prefetch batch 0 e-phase inputs
    int idx0 = beg + ie; if (idx0 >= end) idx0 = end - 1;
    int s_t = esrc[idx0];
    float a_t = as[s_t * NH + ih];
    for (int j0 = beg; j0 < end; j0 += 8) {
        int m = end - j0; if (m > 8) m = 8;
        float e = a_t + adh;
        e = (e > 0.f) ? e : NEG * e;
        float w_t = (ie < m) ? __expf(e) : 0.f;
        den_e += w_t;
        wlds[wv][t] = w_t;                       // [ie][ih] tile, same-wave exchange
        __builtin_amdgcn_wave_barrier();
        // prefetch next batch e-phase inputs (hidden under fma gathers)
        if (j0 + 8 < end) {
            int idx = j0 + 8 + ie; if (idx >= end) idx = end - 1;
            s_t = esrc[idx];
            a_t = as[s_t * NH + ih];
        }
        const int* ep = esrc + j0;               // uniform address -> s_load
        if (m == 8) {
#pragma unroll
            for (int k = 0; k < 8; ++k) {
                int sk = __builtin_amdgcn_readfirstlane(ep[k]);
                float vk = __bfloat162float(h1b[(size_t)sk * HH + t]);
                acc = fmaf(wlds[wv][k * 8 + h], vk, acc);
            }
        } else {
            for (int k = 0; k < m; ++k) {
                int sk = __builtin_amdgcn_readfirstlane(ep[k]);
                float vk = __bfloat162float(h1b[(size_t)sk * HH + t]);
                acc = fmaf(wlds[wv][k * 8 + h], vk, acc);
            }
        }
        __builtin_amdgcn_wave_barrier();
    }
    // den: sum over edge-slot lanes (xor 8/16/32), then remap head index
    den_e += __shfl_xor(den_e, 8);
    den_e += __shfl_xor(den_e, 16);
    den_e += __shfl_xor(den_e, 32);
    float den = __shfl(den_e, h);                // lane h holds head h total
    float o = acc / (den + 1e-16f) + b1[t];
    hmid[(size_t)n * HH + t] = (o > 0.f) ? o : expm1f(o);  // ELU
}

// ---------------- Layer 2 ----------------

// h2b[N,40](bf16) = hmid[N,64] @ W2[64,40]; also a_src2/a_dst2 [N]
__global__ __launch_bounds__(256) void k_gemm2(const float* __restrict__ hmid, const float* __restrict__ W2,
                                               const float* __restrict__ as2w, const float* __restrict__ ad2w,
                                               bf16* __restrict__ h2b, float* __restrict__ as2,
                                               float* __restrict__ ad2) {
    __shared__ float w2s[64 * C2];
    __shared__ float hrow[4][64];
    int t = threadIdx.x;
    for (int i = t; i < 64 * C2; i += 256) w2s[i] = W2[i];
    __syncthreads();
    int wv = t >> 6, ln = t & 63;
    int n = blockIdx.x * 4 + wv;
    hrow[wv][ln] = hmid[(size_t)n * HH + ln];
    __syncthreads();
    float acc = 0.f;
    if (ln < C2) {
#pragma unroll 8
        for (int k = 0; k < 64; ++k) acc = fmaf(hrow[wv][k], w2s[k * C2 + ln], acc);
    }
    float sv = 0.f, dv = 0.f;
    if (ln < C2) {
        h2b[(size_t)n * C2 + ln] = __float2bfloat16(acc);
        sv = acc * as2w[ln];
        dv = acc * ad2w[ln];
    }
#pragma unroll
    for (int off = 32; off > 0; off >>= 1) {
        sv += __shfl_xor(sv, off);
        dv += __shfl_xor(dv, off);
    }
    if (ln == 0) { as2[n] = sv; ad2[n] = dv; }
}

// one wave per node; e-phase: 64 edges (one per lane); fma-phase: s via s_load, w via readlane;
// lane t<40 owns class t; fused log_softmax
__global__ __launch_bounds__(256) void k_aggr2(const bf16* __restrict__ h2b, const float* __restrict__ as2,
                                               const float* __restrict__ ad2, const int* __restrict__ rowptr,
                                               const int* __restrict__ esrc, const float* __restrict__ b2,
                                               float* __restrict__ out) {
    int wv = threadIdx.x >> 6, t = threadIdx.x & 63;
    int n = blockIdx.x * 4 + wv;
    float adn = ad2[n];
    int beg = __builtin_amdgcn_readfirstlane(rowptr[n]);
    int end = __builtin_amdgcn_readfirstlane(rowptr[n + 1]);
    bool act = (t < C2);
    int tc = act ? t : 0;  // clamp: lanes 40..63 duplicate class 0 (discarded)
    float acc = 0.f, den_p = 0.f;
    for (int j0 = beg; j0 < end; j0 += 64) {
        int m = end - j0; if (m > 64) m = 64;
        int idx = j0 + t; if (idx >= end) idx = end - 1;
        int s_t = esrc[idx];
        float e = as2[s_t] + adn;
        e = (e > 0.f) ? e : NEG * e;
        float w_t = (t < m) ? __expf(e) : 0.f;
        den_p += w_t;
        const int* ep = esrc + j0;               // uniform address -> s_load
        int k = 0;
        for (; k + 8 <= m; k += 8) {
#pragma unroll
            for (int u = 0; u < 8; ++u) {
                int sk = __builtin_amdgcn_readfirstlane(ep[k + u]);
                float wk = __shfl(w_t, k + u);   // uniform index -> v_readlane
                acc = fmaf(wk, __bfloat162float(h2b[(size_t)sk * C2 + tc]), acc);
            }
        }
        for (; k < m; ++k) {
            int sk = __builtin_amdgcn_readfirstlane(ep[k]);
            float wk = __shfl(w_t, k);
            acc = fmaf(wk, __bfloat162float(h2b[(size_t)sk * C2 + tc]), acc);
        }
    }
    float den = den_p;
#pragma unroll
    for (int off = 32; off > 0; off >>= 1) den += __shfl_xor(den, off);
    float o = act ? (acc / (den + 1e-16f) + b2[t]) : -1e30f;
    float mx = o;
#pragma unroll
    for (int off = 32; off > 0; off >>= 1) mx = fmaxf(mx, __shfl_xor(mx, off));
    float ex = act ? __expf(o - mx) : 0.f;
    float sm = ex;
#pragma unroll
    for (int off = 32; off > 0; off >>= 1) sm += __shfl_xor(sm, off);
    if (act) out[(size_t)n * C2 + t] = o - mx - logf(sm);
}

// ---------------- launch ----------------

extern "C" void kernel_launch(void* const* d_in, const int* in_sizes, int n_in,
                              void* d_out, int out_size, void* d_ws, size_t ws_size,
                              hipStream_t stream) {
    const float* x    = (const float*)d_in[0];
    const int*   ei   = (const int*)d_in[1];
    const float* W1   = (const float*)d_in[2];
    const float* as1w = (const float*)d_in[3];
    const float* ad1w = (const float*)d_in[4];
    const float* b1   = (const float*)d_in[5];
    const float* W2   = (const float*)d_in[6];
    const float* as2w = (const float*)d_in[7];
    const float* ad2w = (const float*)d_in[8];
    const float* b2   = (const float*)d_in[9];
    float* out = (float*)d_out;

    // workspace layout; CSR temporaries alias later-written buffers (all CSR kernels
    // complete before the aliased partner is first written, same stream)
    char* ws = (char*)d_ws;
    bf16*  h1b     = (bf16*) (ws + 0);            // 12,800,000 B  [N][64]
    float* as1     = (float*)(ws + 12800000);     //  3,200,000 B  [N][8]
    float* ad1     = (float*)(ws + 16000000);     //  3,200,000 B  [N][8]
    float* hmid    = (float*)(ws + 19200000);     // 25,600,000 B  [N][64]
    unsigned int* pb = (unsigned int*)(ws + 19200000); // 13,200,000 B (alias hmid; dead after k_bucket)
    bf16*  h2b     = (bf16*) (ws + 44800000);     //  8,000,000 B  [N][40]
    int*   bhist   = (int*)  (ws + 44800000);     //    630,292 B (alias h2b; dead after k_front2)
    float* as2     = (float*)(ws + 52800000);     //    400,000 B
    int*   bktBase = (int*)  (ws + 52800000);     //      1,568 B (alias as2; dead after k_bucket)
    float* ad2     = (float*)(ws + 53200000);     //    400,000 B
    int*   bktTot  = (int*)  (ws + 53200000);     //      1,564 B (alias ad2; dead after k_base)
    int*   rowp    = (int*)  (ws + 53600000);     //    400,004 B
    int*   esrc    = (int*)  (ws + 54000256);     // 13,200,000 B
    bf16*  Wf      = (bf16*) (ws + 67201024);     //     32,768 B fragment-ordered W1 -> ~67.3 MB

    k_front1<<<NBLK + 64, 256, 0, stream>>>(ei, bhist, W1, Wf);
    k_bscan <<<NBKT, 512, 0, stream>>>(bhist, bktTot);
    k_base  <<<1,    512, 0, stream>>>(bktTot, bktBase, rowp);
    k_front2<<<NBLK + GEMM1_BLKS, 256, 0, stream>>>(ei, bhist, bktBase, pb,
                                                    x, Wf, as1w, ad1w, h1b, as1, ad1);
    k_bucket<<<NBKT, 256, 0, stream>>>(pb, bktBase, rowp, esrc);
    k_aggr1 <<<NNODES / 4, 256, 0, stream>>>(h1b, as1, ad1, rowp, esrc, b1, hmid);
    k_gemm2 <<<NNODES / 4, 256, 0, stream>>>(hmid, W2, as2w, ad2w, h2b, as2, ad2);
    k_aggr2 <<<NNODES / 4, 256, 0, stream>>>(h2b, as2, ad2, rowp, esrc, b2, out);
}

// Round 13
// 331.052 us; speedup vs baseline: 1.0383x; 1.0383x over previous
//
#include <hip/hip_runtime.h>
#include <hip/hip_bf16.h>
#include <cstdint>
#include <cstddef>

#define NNODES 100000
#define NEDGES 3200000
#define NTOT   3300000   // edges + self loops
#define FIN    256
#define HH     64        // heads*hid (layer 1 out)
#define NH     8
#define C2     40
#define NEG    0.2f

// counting-sort params
#define CHUNK  8192
#define NBLK   403       // ceil(NTOT/CHUNK)
#define NBKT   391       // ceil(NNODES/256); bucket(d) = d>>8
#define GEMM1_BLKS 1563  // ceil(NNODES/64)

typedef __hip_bfloat16 bf16;
typedef __attribute__((ext_vector_type(8))) short short8;
typedef __attribute__((ext_vector_type(4))) float f32x4;

// ---------------- fused front-1: bucket histogram (blocks < NBLK) || W1 fragment convert ----------------

__global__ __launch_bounds__(256) void k_front1(const int* __restrict__ ei, int* __restrict__ bhist,
                                                const float* __restrict__ W, bf16* __restrict__ Wf) {
    int t = threadIdx.x;
    if (blockIdx.x < NBLK) {
        __shared__ int h[NBKT];
        for (int b = t; b < NBKT; b += 256) h[b] = 0;
        __syncthreads();
        int i0 = blockIdx.x * CHUNK;
        int i1 = i0 + CHUNK; if (i1 > NTOT) i1 = NTOT;
        for (int i = i0 + t; i < i1; i += 256) {
            int d = (i < NEDGES) ? ei[NEDGES + i] : (i - NEDGES);
            atomicAdd(&h[d >> 8], 1);      // LDS atomic
        }
        __syncthreads();
        for (int b = t; b < NBKT; b += 256) bhist[b * NBLK + blockIdx.x] = h[b];
    } else {
        // W1[256,64] f32 -> Wf bf16 fragment order: Wf[((s*4+f)*64+l)*8+j] = W1[s*32+(l>>4)*8+j][16f+(l&15)]
        int idx = (blockIdx.x - NBLK) * 256 + t;  // < 16384, exact (64 blocks)
        int j = idx & 7, slot = idx >> 3;
        int l = slot & 63, sf = slot >> 6;
        int s = sf >> 2, f = sf & 3;
        int k = s * 32 + (l >> 4) * 8 + j;
        int c = 16 * f + (l & 15);
        Wf[idx] = __float2bfloat16(W[k * HH + c]);
    }
}

// ---------------- CSR scans ----------------

__global__ __launch_bounds__(512) void k_bscan(int* __restrict__ bhist, int* __restrict__ bktTot) {
    __shared__ int sm[512];
    int t = threadIdx.x, b = blockIdx.x;
    int v = (t < NBLK) ? bhist[b * NBLK + t] : 0;
    sm[t] = v;
    __syncthreads();
    for (int off = 1; off < 512; off <<= 1) {
        int u = (t >= off) ? sm[t - off] : 0;
        __syncthreads();
        sm[t] += u;
        __syncthreads();
    }
    if (t < NBLK) bhist[b * NBLK + t] = sm[t] - v;   // exclusive prefix within bucket
    if (t == NBLK - 1) bktTot[b] = sm[t];
}

__global__ __launch_bounds__(512) void k_base(const int* __restrict__ bktTot, int* __restrict__ bktBase,
                                              int* __restrict__ rowptr) {
    __shared__ int sm[512];
    int t = threadIdx.x;
    int v = (t < NBKT) ? bktTot[t] : 0;
    sm[t] = v;
    __syncthreads();
    for (int off = 1; off < 512; off <<= 1) {
        int u = (t >= off) ? sm[t - off] : 0;
        __syncthreads();
        sm[t] += u;
        __syncthreads();
    }
    if (t < NBKT) bktBase[t] = sm[t] - v;
    if (t == NBKT - 1) bktBase[NBKT] = sm[t];
    if (t == 0) rowptr[NNODES] = NTOT;
}

// ---------------- fused front-2: edge scatter (blocks < NBLK) || MFMA gemm1 ----------------

__global__ __launch_bounds__(256) void k_front2(const int* __restrict__ ei, const int* __restrict__ bhist,
                                                const int* __restrict__ bktBase, unsigned int* __restrict__ pb,
                                                const float* __restrict__ x, const bf16* __restrict__ Wf,
                                                const float* __restrict__ asw, const float* __restrict__ adw,
                                                bf16* __restrict__ h1b, float* __restrict__ as,
                                                float* __restrict__ ad) {
    __shared__ int cur[NBKT];
    __shared__ short xs[64][256];   // bf16 bits, 8-elem blocks swizzled: kb' = kb ^ (row&7)
    int t = threadIdx.x;
    if (blockIdx.x < NBLK) {
        // ---- scat1: place packed (src<<8 | dst&255) into bucket-major order via LDS cursors ----
        int blk = blockIdx.x;
        for (int b = t; b < NBKT; b += 256) cur[b] = bktBase[b] + bhist[b * NBLK + blk];
        __syncthreads();
        int i0 = blk * CHUNK;
        int i1 = i0 + CHUNK; if (i1 > NTOT) i1 = NTOT;
        for (int i = i0 + t; i < i1; i += 256) {
            int s, d;
            if (i < NEDGES) { s = ei[i]; d = ei[NEDGES + i]; }
            else            { s = d = i - NEDGES; }
            int p = atomicAdd(&cur[d >> 8], 1);   // LDS atomic
            pb[p] = ((unsigned)s << 8) | (unsigned)(d & 255);
        }
        return;
    }
    // ---- gemm1: h1b[N,64](bf16) = x @ W1 via mfma_f32_16x16x32_bf16; fused att dots ----
    int n0 = (blockIdx.x - NBLK) * 64;
    {
        int r = t >> 2, cq = t & 3;
        int n = n0 + r; if (n >= NNODES) n = NNODES - 1;   // clamp loads; stores guarded
        const float4* xr = (const float4*)(x + (size_t)n * FIN + cq * 64);
        int sw = r & 7;
#pragma unroll
        for (int u = 0; u < 8; ++u) {
            float4 p0 = xr[2 * u], p1 = xr[2 * u + 1];
            float tmp[8] = {p0.x, p0.y, p0.z, p0.w, p1.x, p1.y, p1.z, p1.w};
            short8 v;
#pragma unroll
            for (int e = 0; e < 8; ++e) {
                bf16 b = __float2bfloat16(tmp[e]);
                v[e] = *reinterpret_cast<short*>(&b);
            }
            int kb = cq * 8 + u;
            *(short8*)&xs[r][(kb ^ sw) << 3] = v;
        }
    }
    __syncthreads();
    int l = t & 63, wv = t >> 6;
    int rbase = wv * 16;
    int lr = l & 15, g = l >> 4;
    f32x4 acc[4] = {{0.f,0.f,0.f,0.f},{0.f,0.f,0.f,0.f},{0.f,0.f,0.f,0.f},{0.f,0.f,0.f,0.f}};
    const short8* wfp = (const short8*)Wf;
#pragma unroll 2
    for (int s = 0; s < 8; ++s) {
        short8 a = *(const short8*)&xs[rbase + lr][((s * 4 + g) ^ (lr & 7)) << 3];
#pragma unroll
        for (int f = 0; f < 4; ++f) {
            short8 b = wfp[(s * 4 + f) * 64 + l];
            acc[f] = __builtin_amdgcn_mfma_f32_16x16x32_bf16(a, b, acc[f], 0, 0, 0);
        }
    }
    float awf[4], dwf[4];
#pragma unroll
    for (int f = 0; f < 4; ++f) { awf[f] = asw[16 * f + lr]; dwf[f] = adw[16 * f + lr]; }
    float svv[4][4], dvv[4][4];
#pragma unroll
    for (int f = 0; f < 4; ++f) {
#pragma unroll
        for (int j = 0; j < 4; ++j) {
            float val = acc[f][j];
            int n = n0 + rbase + g * 4 + j;
            if (n < NNODES) h1b[(size_t)n * HH + 16 * f + lr] = __float2bfloat16(val);
            float sv = val * awf[f], dv = val * dwf[f];
            sv += __shfl_xor(sv, 1); sv += __shfl_xor(sv, 2); sv += __shfl_xor(sv, 4);
            dv += __shfl_xor(dv, 1); dv += __shfl_xor(dv, 2); dv += __shfl_xor(dv, 4);
            svv[f][j] = sv; dvv[f][j] = dv;
        }
    }
    if ((l & 7) == 0) {
        int hb = (l >> 3) & 1;   // head = 2f + hb
#pragma unroll
        for (int f = 0; f < 4; ++f) {
            int h = 2 * f + hb;
#pragma unroll
            for (int j = 0; j < 4; ++j) {
                int n = n0 + rbase + g * 4 + j;
                if (n < NNODES) { as[n * NH + h] = svv[f][j]; ad[n * NH + h] = dvv[f][j]; }
            }
        }
    }
}

// ---------------- bucket pass: per-node deg + scan + cursors in LDS; rowptr + final esrc ----------------

__global__ __launch_bounds__(256) void k_bucket(const unsigned int* __restrict__ pb,
                                                const int* __restrict__ bktBase,
                                                int* __restrict__ rowptr, int* __restrict__ esrc) {
    __shared__ int dcnt[256];
    __shared__ int sm[256];
    __shared__ int cur[256];
    int t = threadIdx.x, b = blockIdx.x;
    int base = bktBase[b], cnt = bktBase[b + 1] - base;
    dcnt[t] = 0;
    __syncthreads();
    for (int i = t; i < cnt; i += 256) atomicAdd(&dcnt[pb[base + i] & 255], 1);
    __syncthreads();
    int v = dcnt[t];
    sm[t] = v;
    __syncthreads();
    for (int off = 1; off < 256; off <<= 1) {
        int u = (t >= off) ? sm[t - off] : 0;
        __syncthreads();
        sm[t] += u;
        __syncthreads();
    }
    int ex = sm[t] - v;
    int n = (b << 8) + t;
    if (n < NNODES) rowptr[n] = base + ex;
    cur[t] = base + ex;
    __syncthreads();
    for (int i = t; i < cnt; i += 256) {
        unsigned int e = pb[base + i];
        int p = atomicAdd(&cur[e & 255], 1);  // LDS atomic
        esrc[p] = (int)(e >> 8);
    }
}

// ---------------- Layer 1 aggregation fused with layer-2 GEMM ----------------

// one wave per node; e-phase: 8 edges x 8 heads -> weights in per-wave LDS tile; den in e-phase.
// fma-phase: s via uniform s_load, SGPR row base, weight via LDS [k*8+h]; pipelined prefetch.
// Epilogue (fused gemm2): post-ELU row -> wave-local LDS -> 64x40 dot with W2 (block LDS)
// -> h2b bf16 + attention dots as2/ad2. Eliminates the hmid HBM round-trip entirely.
__global__ __launch_bounds__(256) void k_aggr1(const bf16* __restrict__ h1b, const float* __restrict__ as,
                                               const float* __restrict__ ad, const int* __restrict__ rowptr,
                                               const int* __restrict__ esrc, const float* __restrict__ b1,
                                               const float* __restrict__ W2, const float* __restrict__ as2w,
                                               const float* __restrict__ ad2w, bf16* __restrict__ h2b,
                                               float* __restrict__ as2, float* __restrict__ ad2) {
    __shared__ float wlds[4][64];
    __shared__ float w2s[64 * C2];
    __shared__ float hrow[4][64];
    int tb = threadIdx.x;
    for (int i = tb; i < 64 * C2; i += 256) w2s[i] = W2[i];
    __syncthreads();   // once, before divergent per-wave work
    int wv = tb >> 6, t = tb & 63;
    int n = blockIdx.x * 4 + wv;
    int ih = t & 7;   // e-phase head
    int ie = t >> 3;  // e-phase edge slot
    int h  = t >> 3;  // fma-phase: head of channel t
    float adh = ad[n * NH + ih];
    int beg = __builtin_amdgcn_readfirstlane(rowptr[n]);
    int end = __builtin_amdgcn_readfirstlane(rowptr[n + 1]);
    float acc = 0.f, den_e = 0.f;
    // prefetch batch 0 e-phase inputs
    int idx0 = beg + ie; if (idx0 >= end) idx0 = end - 1;
    int s_t = esrc[idx0];
    float a_t = as[s_t * NH + ih];
    for (int j0 = beg; j0 < end; j0 += 8) {
        int m = end - j0; if (m > 8) m = 8;
        float e = a_t + adh;
        e = (e > 0.f) ? e : NEG * e;
        float w_t = (ie < m) ? __expf(e) : 0.f;
        den_e += w_t;
        wlds[wv][t] = w_t;                       // [ie][ih] tile, same-wave exchange
        __builtin_amdgcn_wave_barrier();
        // prefetch next batch e-phase inputs (hidden under fma gathers)
        if (j0 + 8 < end) {
            int idx = j0 + 8 + ie; if (idx >= end) idx = end - 1;
            s_t = esrc[idx];
            a_t = as[s_t * NH + ih];
        }
        const int* ep = esrc + j0;               // uniform address -> s_load
        if (m == 8) {
#pragma unroll
            for (int k = 0; k < 8; ++k) {
                int sk = __builtin_amdgcn_readfirstlane(ep[k]);
                float vk = __bfloat162float(h1b[(size_t)sk * HH + t]);
                acc = fmaf(wlds[wv][k * 8 + h], vk, acc);
            }
        } else {
            for (int k = 0; k < m; ++k) {
                int sk = __builtin_amdgcn_readfirstlane(ep[k]);
                float vk = __bfloat162float(h1b[(size_t)sk * HH + t]);
                acc = fmaf(wlds[wv][k * 8 + h], vk, acc);
            }
        }
        __builtin_amdgcn_wave_barrier();
    }
    // den: sum over edge-slot lanes (xor 8/16/32), then remap head index
    den_e += __shfl_xor(den_e, 8);
    den_e += __shfl_xor(den_e, 16);
    den_e += __shfl_xor(den_e, 32);
    float den = __shfl(den_e, h);                // lane h holds head h total
    float o = acc / (den + 1e-16f) + b1[t];
    o = (o > 0.f) ? o : expm1f(o);               // ELU
    // ---- fused gemm2: h2[n] = o-row @ W2 (wave-local) ----
    hrow[wv][t] = o;
    __builtin_amdgcn_wave_barrier();
    float sv = 0.f, dv = 0.f;
    if (t < C2) {
        float h2acc = 0.f;
#pragma unroll 8
        for (int k = 0; k < 64; ++k) h2acc = fmaf(hrow[wv][k], w2s[k * C2 + t], h2acc);
        h2b[(size_t)n * C2 + t] = __float2bfloat16(h2acc);
        sv = h2acc * as2w[t];
        dv = h2acc * ad2w[t];
    }
#pragma unroll
    for (int off = 32; off > 0; off >>= 1) {
        sv += __shfl_xor(sv, off);
        dv += __shfl_xor(dv, off);
    }
    if (t == 0) { as2[n] = sv; ad2[n] = dv; }
}

// ---------------- Layer 2 aggregation ----------------

// one wave per node; e-phase: 64 edges (one per lane); fma-phase: s via s_load, w via readlane;
// lane t<40 owns class t; fused log_softmax
__global__ __launch_bounds__(256) void k_aggr2(const bf16* __restrict__ h2b, const float* __restrict__ as2,
                                               const float* __restrict__ ad2, const int* __restrict__ rowptr,
                                               const int* __restrict__ esrc, const float* __restrict__ b2,
                                               float* __restrict__ out) {
    int wv = threadIdx.x >> 6, t = threadIdx.x & 63;
    int n = blockIdx.x * 4 + wv;
    float adn = ad2[n];
    int beg = __builtin_amdgcn_readfirstlane(rowptr[n]);
    int end = __builtin_amdgcn_readfirstlane(rowptr[n + 1]);
    bool act = (t < C2);
    int tc = act ? t : 0;  // clamp: lanes 40..63 duplicate class 0 (discarded)
    float acc = 0.f, den_p = 0.f;
    for (int j0 = beg; j0 < end; j0 += 64) {
        int m = end - j0; if (m > 64) m = 64;
        int idx = j0 + t; if (idx >= end) idx = end - 1;
        int s_t = esrc[idx];
        float e = as2[s_t] + adn;
        e = (e > 0.f) ? e : NEG * e;
        float w_t = (t < m) ? __expf(e) : 0.f;
        den_p += w_t;
        const int* ep = esrc + j0;               // uniform address -> s_load
        int k = 0;
        for (; k + 8 <= m; k += 8) {
#pragma unroll
            for (int u = 0; u < 8; ++u) {
                int sk = __builtin_amdgcn_readfirstlane(ep[k + u]);
                float wk = __shfl(w_t, k + u);   // uniform index -> v_readlane
                acc = fmaf(wk, __bfloat162float(h2b[(size_t)sk * C2 + tc]), acc);
            }
        }
        for (; k < m; ++k) {
            int sk = __builtin_amdgcn_readfirstlane(ep[k]);
            float wk = __shfl(w_t, k);
            acc = fmaf(wk, __bfloat162float(h2b[(size_t)sk * C2 + tc]), acc);
        }
    }
    float den = den_p;
#pragma unroll
    for (int off = 32; off > 0; off >>= 1) den += __shfl_xor(den, off);
    float o = act ? (acc / (den + 1e-16f) + b2[t]) : -1e30f;
    float mx = o;
#pragma unroll
    for (int off = 32; off > 0; off >>= 1) mx = fmaxf(mx, __shfl_xor(mx, off));
    float ex = act ? __expf(o - mx) : 0.f;
    float sm = ex;
#pragma unroll
    for (int off = 32; off > 0; off >>= 1) sm += __shfl_xor(sm, off);
    if (act) out[(size_t)n * C2 + t] = o - mx - logf(sm);
}

// ---------------- launch ----------------

extern "C" void kernel_launch(void* const* d_in, const int* in_sizes, int n_in,
                              void* d_out, int out_size, void* d_ws, size_t ws_size,
                              hipStream_t stream) {
    const float* x    = (const float*)d_in[0];
    const int*   ei   = (const int*)d_in[1];
    const float* W1   = (const float*)d_in[2];
    const float* as1w = (const float*)d_in[3];
    const float* ad1w = (const float*)d_in[4];
    const float* b1   = (const float*)d_in[5];
    const float* W2   = (const float*)d_in[6];
    const float* as2w = (const float*)d_in[7];
    const float* ad2w = (const float*)d_in[8];
    const float* b2   = (const float*)d_in[9];
    float* out = (float*)d_out;

    // workspace layout; CSR temporaries alias later-written buffers (all CSR kernels
    // complete before the aliased partner is first written, same stream)
    char* ws = (char*)d_ws;
    bf16*  h1b     = (bf16*) (ws + 0);            // 12,800,000 B  [N][64]
    float* as1     = (float*)(ws + 12800000);     //  3,200,000 B  [N][8]
    float* ad1     = (float*)(ws + 16000000);     //  3,200,000 B  [N][8]
    unsigned int* pb = (unsigned int*)(ws + 19200000); // 13,200,000 B (dead after k_bucket)
    bf16*  h2b     = (bf16*) (ws + 44800000);     //  8,000,000 B  [N][40]
    int*   bhist   = (int*)  (ws + 44800000);     //    630,292 B (alias h2b; dead after k_front2)
    float* as2     = (float*)(ws + 52800000);     //    400,000 B
    int*   bktBase = (int*)  (ws + 52800000);     //      1,568 B (alias as2; dead after k_bucket)
    float* ad2     = (float*)(ws + 53200000);     //    400,000 B
    int*   bktTot  = (int*)  (ws + 53200000);     //      1,564 B (alias ad2; dead after k_base)
    int*   rowp    = (int*)  (ws + 53600000);     //    400,004 B
    int*   esrc    = (int*)  (ws + 54000256);     // 13,200,000 B
    bf16*  Wf      = (bf16*) (ws + 67201024);     //     32,768 B fragment-ordered W1 -> ~67.3 MB

    k_front1<<<NBLK + 64, 256, 0, stream>>>(ei, bhist, W1, Wf);
    k_bscan <<<NBKT, 512, 0, stream>>>(bhist, bktTot);
    k_base  <<<1,    512, 0, stream>>>(bktTot, bktBase, rowp);
    k_front2<<<NBLK + GEMM1_BLKS, 256, 0, stream>>>(ei, bhist, bktBase, pb,
                                                    x, Wf, as1w, ad1w, h1b, as1, ad1);
    k_bucket<<<NBKT, 256, 0, stream>>>(pb, bktBase, rowp, esrc);
    k_aggr1 <<<NNODES / 4, 256, 0, stream>>>(h1b, as1, ad1, rowp, esrc, b1,
                                             W2, as2w, ad2w, h2b, as2, ad2);
    k_aggr2 <<<NNODES / 4, 256, 0, stream>>>(h2b, as2, ad2, rowp, esrc, b2, out);
}

// Round 14
// 313.505 us; speedup vs baseline: 1.0964x; 1.0560x over previous
//
#include <hip/hip_runtime.h>
#include <hip/hip_bf16.h>
#include <cstdint>
#include <cstddef>

#define NNODES 100000
#define NEDGES 3200000
#define NTOT   3300000   // edges + self loops
#define FIN    256
#define HH     64        // heads*hid (layer 1 out)
#define NH     8
#define C2     40
#define NEG    0.2f

// counting-sort params
#define CHUNK  8192
#define NBLK   403       // ceil(NTOT/CHUNK)
#define NBKT   391       // ceil(NNODES/256); bucket(d) = d>>8
#define GEMM1_BLKS 1563  // ceil(NNODES/64)

typedef __hip_bfloat16 bf16;
typedef __attribute__((ext_vector_type(8))) short short8;
typedef __attribute__((ext_vector_type(4))) float f32x4;

// ---------------- fused front-1: bucket histogram (blocks < NBLK) || W1 fragment convert ----------------

__global__ __launch_bounds__(256) void k_front1(const int* __restrict__ ei, int* __restrict__ bhist,
                                                const float* __restrict__ W, bf16* __restrict__ Wf) {
    int t = threadIdx.x;
    if (blockIdx.x < NBLK) {
        __shared__ int h[NBKT];
        for (int b = t; b < NBKT; b += 256) h[b] = 0;
        __syncthreads();
        int i0 = blockIdx.x * CHUNK;
        int i1 = i0 + CHUNK; if (i1 > NTOT) i1 = NTOT;
        for (int i = i0 + t; i < i1; i += 256) {
            int d = (i < NEDGES) ? ei[NEDGES + i] : (i - NEDGES);
            atomicAdd(&h[d >> 8], 1);      // LDS atomic
        }
        __syncthreads();
        for (int b = t; b < NBKT; b += 256) bhist[b * NBLK + blockIdx.x] = h[b];
    } else {
        // W1[256,64] f32 -> Wf bf16 fragment order: Wf[((s*4+f)*64+l)*8+j] = W1[s*32+(l>>4)*8+j][16f+(l&15)]
        int idx = (blockIdx.x - NBLK) * 256 + t;  // < 16384, exact (64 blocks)
        int j = idx & 7, slot = idx >> 3;
        int l = slot & 63, sf = slot >> 6;
        int s = sf >> 2, f = sf & 3;
        int k = s * 32 + (l >> 4) * 8 + j;
        int c = 16 * f + (l & 15);
        Wf[idx] = __float2bfloat16(W[k * HH + c]);
    }
}

// ---------------- CSR scans ----------------

__global__ __launch_bounds__(512) void k_bscan(int* __restrict__ bhist, int* __restrict__ bktTot) {
    __shared__ int sm[512];
    int t = threadIdx.x, b = blockIdx.x;
    int v = (t < NBLK) ? bhist[b * NBLK + t] : 0;
    sm[t] = v;
    __syncthreads();
    for (int off = 1; off < 512; off <<= 1) {
        int u = (t >= off) ? sm[t - off] : 0;
        __syncthreads();
        sm[t] += u;
        __syncthreads();
    }
    if (t < NBLK) bhist[b * NBLK + t] = sm[t] - v;   // exclusive prefix within bucket
    if (t == NBLK - 1) bktTot[b] = sm[t];
}

__global__ __launch_bounds__(512) void k_base(const int* __restrict__ bktTot, int* __restrict__ bktBase,
                                              int* __restrict__ rowptr) {
    __shared__ int sm[512];
    int t = threadIdx.x;
    int v = (t < NBKT) ? bktTot[t] : 0;
    sm[t] = v;
    __syncthreads();
    for (int off = 1; off < 512; off <<= 1) {
        int u = (t >= off) ? sm[t - off] : 0;
        __syncthreads();
        sm[t] += u;
        __syncthreads();
    }
    if (t < NBKT) bktBase[t] = sm[t] - v;
    if (t == NBKT - 1) bktBase[NBKT] = sm[t];
    if (t == 0) rowptr[NNODES] = NTOT;
}

// ---------------- fused front-2: edge scatter (blocks < NBLK) || MFMA gemm1 ----------------

__global__ __launch_bounds__(256) void k_front2(const int* __restrict__ ei, const int* __restrict__ bhist,
                                                const int* __restrict__ bktBase, unsigned int* __restrict__ pb,
                                                const float* __restrict__ x, const bf16* __restrict__ Wf,
                                                const float* __restrict__ asw, const float* __restrict__ adw,
                                                bf16* __restrict__ h1b, float* __restrict__ as,
                                                float* __restrict__ ad) {
    __shared__ int cur[NBKT];
    __shared__ short xs[64][256];   // bf16 bits, 8-elem blocks swizzled: kb' = kb ^ (row&7)
    int t = threadIdx.x;
    if (blockIdx.x < NBLK) {
        // ---- scat1: place packed (src<<8 | dst&255) into bucket-major order via LDS cursors ----
        int blk = blockIdx.x;
        for (int b = t; b < NBKT; b += 256) cur[b] = bktBase[b] + bhist[b * NBLK + blk];
        __syncthreads();
        int i0 = blk * CHUNK;
        int i1 = i0 + CHUNK; if (i1 > NTOT) i1 = NTOT;
        for (int i = i0 + t; i < i1; i += 256) {
            int s, d;
            if (i < NEDGES) { s = ei[i]; d = ei[NEDGES + i]; }
            else            { s = d = i - NEDGES; }
            int p = atomicAdd(&cur[d >> 8], 1);   // LDS atomic
            pb[p] = ((unsigned)s << 8) | (unsigned)(d & 255);
        }
        return;
    }
    // ---- gemm1: h1b[N,64](bf16) = x @ W1 via mfma_f32_16x16x32_bf16; fused att dots ----
    int n0 = (blockIdx.x - NBLK) * 64;
    {
        int r = t >> 2, cq = t & 3;
        int n = n0 + r; if (n >= NNODES) n = NNODES - 1;   // clamp loads; stores guarded
        const float4* xr = (const float4*)(x + (size_t)n * FIN + cq * 64);
        int sw = r & 7;
#pragma unroll
        for (int u = 0; u < 8; ++u) {
            float4 p0 = xr[2 * u], p1 = xr[2 * u + 1];
            float tmp[8] = {p0.x, p0.y, p0.z, p0.w, p1.x, p1.y, p1.z, p1.w};
            short8 v;
#pragma unroll
            for (int e = 0; e < 8; ++e) {
                bf16 b = __float2bfloat16(tmp[e]);
                v[e] = *reinterpret_cast<short*>(&b);
            }
            int kb = cq * 8 + u;
            *(short8*)&xs[r][(kb ^ sw) << 3] = v;
        }
    }
    __syncthreads();
    int l = t & 63, wv = t >> 6;
    int rbase = wv * 16;
    int lr = l & 15, g = l >> 4;
    f32x4 acc[4] = {{0.f,0.f,0.f,0.f},{0.f,0.f,0.f,0.f},{0.f,0.f,0.f,0.f},{0.f,0.f,0.f,0.f}};
    const short8* wfp = (const short8*)Wf;
#pragma unroll 2
    for (int s = 0; s < 8; ++s) {
        short8 a = *(const short8*)&xs[rbase + lr][((s * 4 + g) ^ (lr & 7)) << 3];
#pragma unroll
        for (int f = 0; f < 4; ++f) {
            short8 b = wfp[(s * 4 + f) * 64 + l];
            acc[f] = __builtin_amdgcn_mfma_f32_16x16x32_bf16(a, b, acc[f], 0, 0, 0);
        }
    }
    float awf[4], dwf[4];
#pragma unroll
    for (int f = 0; f < 4; ++f) { awf[f] = asw[16 * f + lr]; dwf[f] = adw[16 * f + lr]; }
    float svv[4][4], dvv[4][4];
#pragma unroll
    for (int f = 0; f < 4; ++f) {
#pragma unroll
        for (int j = 0; j < 4; ++j) {
            float val = acc[f][j];
            int n = n0 + rbase + g * 4 + j;
            if (n < NNODES) h1b[(size_t)n * HH + 16 * f + lr] = __float2bfloat16(val);
            float sv = val * awf[f], dv = val * dwf[f];
            sv += __shfl_xor(sv, 1); sv += __shfl_xor(sv, 2); sv += __shfl_xor(sv, 4);
            dv += __shfl_xor(dv, 1); dv += __shfl_xor(dv, 2); dv += __shfl_xor(dv, 4);
            svv[f][j] = sv; dvv[f][j] = dv;
        }
    }
    if ((l & 7) == 0) {
        int hb = (l >> 3) & 1;   // head = 2f + hb
#pragma unroll
        for (int f = 0; f < 4; ++f) {
            int h = 2 * f + hb;
#pragma unroll
            for (int j = 0; j < 4; ++j) {
                int n = n0 + rbase + g * 4 + j;
                if (n < NNODES) { as[n * NH + h] = svv[f][j]; ad[n * NH + h] = dvv[f][j]; }
            }
        }
    }
}

// ---------------- bucket pass: per-node deg + scan + cursors in LDS; rowptr + final esrc ----------------

__global__ __launch_bounds__(256) void k_bucket(const unsigned int* __restrict__ pb,
                                                const int* __restrict__ bktBase,
                                                int* __restrict__ rowptr, int* __restrict__ esrc) {
    __shared__ int dcnt[256];
    __shared__ int sm[256];
    __shared__ int cur[256];
    int t = threadIdx.x, b = blockIdx.x;
    int base = bktBase[b], cnt = bktBase[b + 1] - base;
    dcnt[t] = 0;
    __syncthreads();
    for (int i = t; i < cnt; i += 256) atomicAdd(&dcnt[pb[base + i] & 255], 1);
    __syncthreads();
    int v = dcnt[t];
    sm[t] = v;
    __syncthreads();
    for (int off = 1; off < 256; off <<= 1) {
        int u = (t >= off) ? sm[t - off] : 0;
        __syncthreads();
        sm[t] += u;
        __syncthreads();
    }
    int ex = sm[t] - v;
    int n = (b << 8) + t;
    if (n < NNODES) rowptr[n] = base + ex;
    cur[t] = base + ex;
    __syncthreads();
    for (int i = t; i < cnt; i += 256) {
        unsigned int e = pb[base + i];
        int p = atomicAdd(&cur[e & 255], 1);  // LDS atomic
        esrc[p] = (int)(e >> 8);
    }
}

// ---------------- Layer 1 aggregation fused with layer-2 GEMM (16 nodes/block) ----------------

// Each wave processes 4 consecutive nodes sequentially; W2 LDS load + entry barrier amortize 4x.
// Per node: e-phase 8 edges x 8 heads -> wlds; fma-phase s via uniform s_load, w via LDS; then
// fused gemm2 epilogue: post-ELU row -> hrow -> 64x40 dot -> h2b/as2/ad2. No hmid round-trip.
__global__ __launch_bounds__(256) void k_aggr1(const bf16* __restrict__ h1b, const float* __restrict__ as,
                                               const float* __restrict__ ad, const int* __restrict__ rowptr,
                                               const int* __restrict__ esrc, const float* __restrict__ b1,
                                               const float* __restrict__ W2, const float* __restrict__ as2w,
                                               const float* __restrict__ ad2w, bf16* __restrict__ h2b,
                                               float* __restrict__ as2, float* __restrict__ ad2) {
    __shared__ float wlds[4][64];
    __shared__ float w2s[64 * C2];
    __shared__ float hrow[4][64];
    int tb = threadIdx.x;
    for (int i = tb; i < 64 * C2; i += 256) w2s[i] = W2[i];
    __syncthreads();   // once per block, before divergent per-wave work
    int wv = tb >> 6, t = tb & 63;
    int ih = t & 7;   // e-phase head
    int ie = t >> 3;  // e-phase edge slot
    int h  = t >> 3;  // fma-phase: head of channel t
    float b1t = b1[t];
    bool act = (t < C2);
    float a2wt = act ? as2w[t] : 0.f;
    float d2wt = act ? ad2w[t] : 0.f;
    int nbase = blockIdx.x * 16 + wv * 4;
    for (int ni = 0; ni < 4; ++ni) {
        int n = nbase + ni;
        float adh = ad[n * NH + ih];
        int beg = __builtin_amdgcn_readfirstlane(rowptr[n]);
        int end = __builtin_amdgcn_readfirstlane(rowptr[n + 1]);
        float acc = 0.f, den_e = 0.f;
        // prefetch batch 0 e-phase inputs
        int idx0 = beg + ie; if (idx0 >= end) idx0 = end - 1;
        int s_t = esrc[idx0];
        float a_t = as[s_t * NH + ih];
        for (int j0 = beg; j0 < end; j0 += 8) {
            int m = end - j0; if (m > 8) m = 8;
            float e = a_t + adh;
            e = (e > 0.f) ? e : NEG * e;
            float w_t = (ie < m) ? __expf(e) : 0.f;
            den_e += w_t;
            wlds[wv][t] = w_t;                       // [ie][ih] tile, same-wave exchange
            __builtin_amdgcn_wave_barrier();
            // prefetch next batch e-phase inputs (hidden under fma gathers)
            if (j0 + 8 < end) {
                int idx = j0 + 8 + ie; if (idx >= end) idx = end - 1;
                s_t = esrc[idx];
                a_t = as[s_t * NH + ih];
            }
            const int* ep = esrc + j0;               // uniform address -> s_load
            if (m == 8) {
#pragma unroll
                for (int k = 0; k < 8; ++k) {
                    int sk = __builtin_amdgcn_readfirstlane(ep[k]);
                    float vk = __bfloat162float(h1b[(size_t)sk * HH + t]);
                    acc = fmaf(wlds[wv][k * 8 + h], vk, acc);
                }
            } else {
                for (int k = 0; k < m; ++k) {
                    int sk = __builtin_amdgcn_readfirstlane(ep[k]);
                    float vk = __bfloat162float(h1b[(size_t)sk * HH + t]);
                    acc = fmaf(wlds[wv][k * 8 + h], vk, acc);
                }
            }
            __builtin_amdgcn_wave_barrier();
        }
        // den: sum over edge-slot lanes (xor 8/16/32), then remap head index
        den_e += __shfl_xor(den_e, 8);
        den_e += __shfl_xor(den_e, 16);
        den_e += __shfl_xor(den_e, 32);
        float den = __shfl(den_e, h);                // lane h holds head h total
        float o = acc / (den + 1e-16f) + b1t;
        o = (o > 0.f) ? o : expm1f(o);               // ELU
        // ---- fused gemm2: h2[n] = o-row @ W2 (wave-local) ----
        hrow[wv][t] = o;
        __builtin_amdgcn_wave_barrier();
        float sv = 0.f, dv = 0.f;
        if (act) {
            float h2acc = 0.f;
#pragma unroll 8
            for (int k = 0; k < 64; ++k) h2acc = fmaf(hrow[wv][k], w2s[k * C2 + t], h2acc);
            h2b[(size_t)n * C2 + t] = __float2bfloat16(h2acc);
            sv = h2acc * a2wt;
            dv = h2acc * d2wt;
        }
#pragma unroll
        for (int off = 32; off > 0; off >>= 1) {
            sv += __shfl_xor(sv, off);
            dv += __shfl_xor(dv, off);
        }
        if (t == 0) { as2[n] = sv; ad2[n] = dv; }
        __builtin_amdgcn_wave_barrier();             // hrow/wlds reuse safety across ni
    }
}

// ---------------- Layer 2 aggregation ----------------

// one wave per node; e-phase: 64 edges (one per lane); fma-phase: s via s_load, w via readlane;
// lane t<40 owns class t; fused log_softmax
__global__ __launch_bounds__(256) void k_aggr2(const bf16* __restrict__ h2b, const float* __restrict__ as2,
                                               const float* __restrict__ ad2, const int* __restrict__ rowptr,
                                               const int* __restrict__ esrc, const float* __restrict__ b2,
                                               float* __restrict__ out) {
    int wv = threadIdx.x >> 6, t = threadIdx.x & 63;
    int n = blockIdx.x * 4 + wv;
    float adn = ad2[n];
    int beg = __builtin_amdgcn_readfirstlane(rowptr[n]);
    int end = __builtin_amdgcn_readfirstlane(rowptr[n + 1]);
    bool act = (t < C2);
    int tc = act ? t : 0;  // clamp: lanes 40..63 duplicate class 0 (discarded)
    float acc = 0.f, den_p = 0.f;
    for (int j0 = beg; j0 < end; j0 += 64) {
        int m = end - j0; if (m > 64) m = 64;
        int idx = j0 + t; if (idx >= end) idx = end - 1;
        int s_t = esrc[idx];
        float e = as2[s_t] + adn;
        e = (e > 0.f) ? e : NEG * e;
        float w_t = (t < m) ? __expf(e) : 0.f;
        den_p += w_t;
        const int* ep = esrc + j0;               // uniform address -> s_load
        int k = 0;
        for (; k + 8 <= m; k += 8) {
#pragma unroll
            for (int u = 0; u < 8; ++u) {
                int sk = __builtin_amdgcn_readfirstlane(ep[k + u]);
                float wk = __shfl(w_t, k + u);   // uniform index -> v_readlane
                acc = fmaf(wk, __bfloat162float(h2b[(size_t)sk * C2 + tc]), acc);
            }
        }
        for (; k < m; ++k) {
            int sk = __builtin_amdgcn_readfirstlane(ep[k]);
            float wk = __shfl(w_t, k);
            acc = fmaf(wk, __bfloat162float(h2b[(size_t)sk * C2 + tc]), acc);
        }
    }
    float den = den_p;
#pragma unroll
    for (int off = 32; off > 0; off >>= 1) den += __shfl_xor(den, off);
    float o = act ? (acc / (den + 1e-16f) + b2[t]) : -1e30f;
    float mx = o;
#pragma unroll
    for (int off = 32; off > 0; off >>= 1) mx = fmaxf(mx, __shfl_xor(mx, off));
    float ex = act ? __expf(o - mx) : 0.f;
    float sm = ex;
#pragma unroll
    for (int off = 32; off > 0; off >>= 1) sm += __shfl_xor(sm, off);
    if (act) out[(size_t)n * C2 + t] = o - mx - logf(sm);
}

// ---------------- launch ----------------

extern "C" void kernel_launch(void* const* d_in, const int* in_sizes, int n_in,
                              void* d_out, int out_size, void* d_ws, size_t ws_size,
                              hipStream_t stream) {
    const float* x    = (const float*)d_in[0];
    const int*   ei   = (const int*)d_in[1];
    const float* W1   = (const float*)d_in[2];
    const float* as1w = (const float*)d_in[3];
    const float* ad1w = (const float*)d_in[4];
    const float* b1   = (const float*)d_in[5];
    const float* W2   = (const float*)d_in[6];
    const float* as2w = (const float*)d_in[7];
    const float* ad2w = (const float*)d_in[8];
    const float* b2   = (const float*)d_in[9];
    float* out = (float*)d_out;

    // workspace layout; CSR temporaries alias later-written buffers (all CSR kernels
    // complete before the aliased partner is first written, same stream)
    char* ws = (char*)d_ws;
    bf16*  h1b     = (bf16*) (ws + 0);            // 12,800,000 B  [N][64]
    float* as1     = (float*)(ws + 12800000);     //  3,200,000 B  [N][8]
    float* ad1     = (float*)(ws + 16000000);     //  3,200,000 B  [N][8]
    unsigned int* pb = (unsigned int*)(ws + 19200000); // 13,200,000 B (dead after k_bucket)
    bf16*  h2b     = (bf16*) (ws + 44800000);     //  8,000,000 B  [N][40]
    int*   bhist   = (int*)  (ws + 44800000);     //    630,292 B (alias h2b; dead after k_front2)
    float* as2     = (float*)(ws + 52800000);     //    400,000 B
    int*   bktBase = (int*)  (ws + 52800000);     //      1,568 B (alias as2; dead after k_bucket)
    float* ad2     = (float*)(ws + 53200000);     //    400,000 B
    int*   bktTot  = (int*)  (ws + 53200000);     //      1,564 B (alias ad2; dead after k_base)
    int*   rowp    = (int*)  (ws + 53600000);     //    400,004 B
    int*   esrc    = (int*)  (ws + 54000256);     // 13,200,000 B
    bf16*  Wf      = (bf16*) (ws + 67201024);     //     32,768 B fragment-ordered W1 -> ~67.3 MB

    k_front1<<<NBLK + 64, 256, 0, stream>>>(ei, bhist, W1, Wf);
    k_bscan <<<NBKT, 512, 0, stream>>>(bhist, bktTot);
    k_base  <<<1,    512, 0, stream>>>(bktTot, bktBase, rowp);
    k_front2<<<NBLK + GEMM1_BLKS, 256, 0, stream>>>(ei, bhist, bktBase, pb,
                                                    x, Wf, as1w, ad1w, h1b, as1, ad1);
    k_bucket<<<NBKT, 256, 0, stream>>>(pb, bktBase, rowp, esrc);
    k_aggr1 <<<NNODES / 16, 256, 0, stream>>>(h1b, as1, ad1, rowp, esrc, b1,
                                              W2, as2w, ad2w, h2b, as2, ad2);
    k_aggr2 <<<NNODES / 4, 256, 0, stream>>>(h2b, as2, ad2, rowp, esrc, b2, out);
}